// Round 15
// baseline (868.205 us; speedup 1.0000x reference)
//
#include <hip/hip_runtime.h>
#include <stdint.h>

typedef float  f32x4  __attribute__((ext_vector_type(4)));
typedef short  bf16x8 __attribute__((ext_vector_type(8)));

#define TYPES 10
#define D_IN  128
#define D_H1  512
#define D_H2  512
#define D_OUT 256

__device__ __forceinline__ unsigned short f2bf(float f) {
  union { float f; unsigned u; } v; v.f = f;
  unsigned u = v.u;
  return (unsigned short)((u + 0x7FFFu + ((u >> 16) & 1u)) >> 16);  // RTNE
}

__device__ __forceinline__ void async16(void* lds, const void* g) {
  __builtin_amdgcn_global_load_lds(
      (const __attribute__((address_space(1))) void*)g,
      (__attribute__((address_space(3))) void*)lds, 16, 0, 0);
}

// meta: [0..9] counts, [16..26] padded offsets (multiples of 256), [32..41] cursors
__global__ void k_init(int* meta) {
  if (threadIdx.x < 48) meta[threadIdx.x] = 0;
}

__global__ void k_hist(const int* __restrict__ types, int n, int* __restrict__ meta) {
  __shared__ int lc[TYPES];
  if (threadIdx.x < TYPES) lc[threadIdx.x] = 0;
  __syncthreads();
  int i = blockIdx.x * 256 + threadIdx.x;
  if (i < n) atomicAdd(&lc[types[i]], 1);
  __syncthreads();
  if (threadIdx.x < TYPES && lc[threadIdx.x]) atomicAdd(&meta[threadIdx.x], lc[threadIdx.x]);
}

__global__ void k_scan(int* meta) {
  if (threadIdx.x == 0) {
    int off = 0;
    for (int t = 0; t < TYPES; ++t) {
      meta[16 + t] = off;
      off += ((meta[t] + 255) >> 8) << 8;
    }
    meta[26] = off;
  }
}

__global__ void k_scatter(const int* __restrict__ types, int n,
                          int* __restrict__ meta, int* __restrict__ perm) {
  __shared__ int lc[TYPES], lbase[TYPES];
  if (threadIdx.x < TYPES) lc[threadIdx.x] = 0;
  __syncthreads();
  int i = blockIdx.x * 256 + threadIdx.x;
  int t = 0, loc = 0;
  bool ok = i < n;
  if (ok) { t = types[i]; loc = atomicAdd(&lc[t], 1); }
  __syncthreads();
  if (threadIdx.x < TYPES) {
    int c = lc[threadIdx.x];
    lbase[threadIdx.x] = c ? atomicAdd(&meta[32 + threadIdx.x], c) : 0;
  }
  __syncthreads();
  if (ok) perm[meta[16 + t] + lbase[t] + loc] = i;
}

// gather rows into sorted order, fp32 -> bf16; zero the padding rows
__global__ void k_gather(const float* __restrict__ x, const int* __restrict__ perm,
                         const int* __restrict__ meta, unsigned short* __restrict__ xs) {
  int p = blockIdx.x * 8 + (threadIdx.x >> 5);
  if (p >= meta[26]) return;
  int t = 0;
  while (p >= meta[17 + t]) t++;
  int e = (threadIdx.x & 31) * 4;
  unsigned short o0, o1, o2, o3;
  if (p - meta[16 + t] < meta[t]) {
    const float4 v = *(const float4*)(x + (size_t)perm[p] * D_IN + e);
    o0 = f2bf(v.x); o1 = f2bf(v.y); o2 = f2bf(v.z); o3 = f2bf(v.w);
  } else {
    o0 = o1 = o2 = o3 = 0;
  }
  *(ushort4*)(xs + (size_t)p * D_IN + e) = make_ushort4(o0, o1, o2, o3);
}

// W[t] (K x NOUT) fp32 -> Wt[t] (NOUT x K) bf16, all layers in one launch
__global__ void k_wtrans_all(const float* __restrict__ W0a, const float* __restrict__ W1a,
                             const float* __restrict__ W2a,
                             unsigned short* __restrict__ wt0, unsigned short* __restrict__ wt1,
                             unsigned short* __restrict__ wt2) {
  int b = blockIdx.x;
  const float* W; unsigned short* Wt; int K, NOUT, t, local;
  if (b < 160)      { W = W0a; Wt = wt0; K = 128; NOUT = 512; t = b / 16; local = b % 16; }
  else if (b < 800) { b -= 160; W = W1a; Wt = wt1; K = 512; NOUT = 512; t = b / 64; local = b % 64; }
  else              { b -= 800; W = W2a; Wt = wt2; K = 512; NOUT = 256; t = b / 32; local = b % 32; }
  int ntn = NOUT >> 6;
  int kb = local / ntn, nb = local % ntn;
  __shared__ unsigned short tile[64][65];
  const float* src = W + (size_t)t * K * NOUT + (size_t)(kb * 64) * NOUT + nb * 64;
  int c = threadIdx.x & 63;
  int r0 = threadIdx.x >> 6;
  #pragma unroll
  for (int i = 0; i < 16; ++i) {
    int r = r0 * 16 + i;
    tile[r][c] = f2bf(src[(size_t)r * NOUT + c]);
  }
  __syncthreads();
  unsigned short* dst = Wt + (size_t)t * NOUT * K + (size_t)(nb * 64) * K + kb * 64;
  #pragma unroll
  for (int i = 0; i < 16; ++i) {
    int nn = r0 * 16 + i;
    dst[(size_t)nn * K + c] = tile[c][nn];
  }
}

// ---------------------------------------------------------------------------
// R15: k_gemmR — B-operand from GLOBAL->VGPR (no LDS for B), breaking the
// LDS-BW wall. Per-CU per K-tile LDS traffic: old (2Mx4N, A+B in LDS) =
// A*4 + B*2 = 192KB >= 1536 cyc >> 621 cyc MFMA (the invariant plateau).
// New (4Mx2N, A-only in LDS) = A*2 = 64KB ~ 500-750 cyc < 621 cyc MFMA.
// Wave = 64 rows x 128 cols; acc[4][8] (128 VGPR); B double-buffered in regs
// (bA/bB ping-pong, compile-time), loaded 1 K-tile ahead, compiler-tracked
// waits for the reg dependencies. A: 3-slot LDS rotation (slot = g%3, 32KB
// each), staged 2 tiles ahead via global_load_lds (pre-swizzled source,
// reads XOR (R&7)<<4, 2-way = free). Cross-wave A protocol per tile end:
// oldest 4 outstanding vmem ops are A(g+1) (pre-fence, robust to intra-tile
// issue reordering) -> vmcnt(20) steady / 16 at g=nKT-2 / 0 at last tile;
// then s_barrier; sched_barrier(0) at tile top pins next reads below it.
// ---------------------------------------------------------------------------
__launch_bounds__(512, 2)
__global__ void k_gemmR(const unsigned short* __restrict__ A,
                        const unsigned short* __restrict__ Wt,
                        const float* __restrict__ bias,
                        unsigned short* __restrict__ H,
                        const int* __restrict__ meta) {
  constexpr int K = 512, NOUT = 512, nKT = 8, K2 = K * 2;
  __shared__ char lds[131072];   // A slots 0..96KB; epilogue C-buf 128KB

  // bijective XCD-aware swizzle (m204), 2-D grid
  int NXB = gridDim.x;
  int nwg = NXB * (int)gridDim.y;
  int raw = blockIdx.x + blockIdx.y * NXB;
  int q = nwg >> 3, rr = nwg & 7;
  int xcd = raw & 7, idx = raw >> 3;
  int swz = (xcd < rr ? xcd * (q + 1) : rr * (q + 1) + (xcd - rr) * q) + idx;
  int bx = swz % NXB, by = swz / NXB;

  int row0 = by * 256;
  if (row0 >= meta[26]) return;
  int t = 0;
  while (row0 >= meta[17 + t]) t++;
  int tid = threadIdx.x, lane = tid & 63, wid = tid >> 6;
  int mrow = (wid >> 1) * 64;      // 4 M-groups of 64 rows
  int ncg  = wid & 1;              // 2 N-groups of 128 cols
  int col0 = bx * 256;
  const char* Ag = (const char*)(A + (size_t)row0 * K);
  const char* Bg = (const char*)(Wt + ((size_t)t * NOUT + col0) * K);

  // A staging: unit 32KB = 256 rows x 128B; thread covers 4 async16.
  // dest row r = i*64 + wid*8 + (lane>>3); r&7 == (lane>>3)&7; source granule
  // = (lane&7) ^ (r&7)  (pre-swizzle so linear LDS + XOR read works).
  int gsrc = ((tid & 7) ^ ((tid >> 3) & 7)) * 16;
  const char* aS = Ag + (size_t)(tid >> 3) * K2 + gsrc;
  auto stageA = [&](int kt) {
    if (kt >= nKT) return;
    char* dst = lds + (kt % 3) * 32768 + wid * 1024;
    const char* src = aS + (size_t)kt * 128;
    #pragma unroll
    for (int i = 0; i < 4; ++i)
      async16(dst + i * 8192, src + (size_t)(i * 64) * K2);
  };

  // B fragment global base: lane l covers col (l&15), k-bytes (l>>4)*16.
  const char* bP = Bg + (size_t)(ncg * 128 + (lane & 15)) * K2 + (lane >> 4) * 16;
  bf16x8 bA[8][2], bB[8][2];
  auto loadB = [&](bf16x8 (&bb)[8][2], int kt) {
    if (kt >= nKT) return;
    #pragma unroll
    for (int n = 0; n < 8; ++n)
      #pragma unroll
      for (int kk = 0; kk < 2; ++kk)
        bb[n][kk] = *(const bf16x8*)(bP + (size_t)n * 16 * K2 + kt * 128 + kk * 64);
  };

  f32x4 acc[4][8] = {};
  int rA = lane & 15, qk = (lane >> 4) * 16;
  bf16x8 a[4][2];

  // prologue: B(0) regs + A(0),A(1) slots; full drain once (cheap, one-time)
  loadB(bA, 0); stageA(0); stageA(1);
  asm volatile("s_waitcnt vmcnt(0)" ::: "memory");
  __builtin_amdgcn_s_barrier();

  auto tile = [&](int g, bf16x8 (&bcur)[8][2], bf16x8 (&bnext)[8][2]) {
    __builtin_amdgcn_sched_barrier(0);      // pin reads below the preceding barrier
    const char* As = lds + (g % 3) * 32768;
    #pragma unroll
    for (int m = 0; m < 4; ++m) {
      int R = mrow + m * 16 + rA;
      #pragma unroll
      for (int kk = 0; kk < 2; ++kk)
        a[m][kk] = *(const bf16x8*)(As + R * 128 + ((kk * 64 + qk) ^ ((R & 7) << 4)));
    }
    loadB(bnext, g + 1);                    // 16 global loads -> regs
    stageA(g + 2);                          // 4 gload_lds -> slot (g+2)%3
    __builtin_amdgcn_s_setprio(1);
    #pragma unroll
    for (int kk = 0; kk < 2; ++kk)
      #pragma unroll
      for (int m = 0; m < 4; ++m)
        #pragma unroll
        for (int n = 0; n < 8; ++n)
          acc[m][n] = __builtin_amdgcn_mfma_f32_16x16x32_bf16(
              a[m][kk], bcur[n][kk], acc[m][n], 0, 0, 0);
    __builtin_amdgcn_s_setprio(0);
    // cross-wave A protocol: drain A(g+1) (the oldest 4 pre-fence ops).
    if (g + 2 < nKT)      asm volatile("s_waitcnt vmcnt(20)" ::: "memory");
    else if (g + 1 < nKT) asm volatile("s_waitcnt vmcnt(16)" ::: "memory");
    else                  asm volatile("s_waitcnt vmcnt(0)" ::: "memory");
    __builtin_amdgcn_s_barrier();
  };
  #pragma unroll
  for (int j = 0; j < nKT / 2; ++j) { tile(2 * j, bA, bB); tile(2 * j + 1, bB, bA); }

  // epilogue: acc -> LDS (256 rows x 256 bf16, XOR-swizzled) -> coalesced H
  int cA = lane & 15, rE = (lane >> 4) * 4;
  char* cb = (char*)lds;
  float bv[8];
  #pragma unroll
  for (int n = 0; n < 8; ++n) bv[n] = bias[t * NOUT + col0 + ncg * 128 + n * 16 + cA];
  #pragma unroll
  for (int m = 0; m < 4; ++m)
    #pragma unroll
    for (int e = 0; e < 4; ++e) {
      int row = mrow + m * 16 + rE + e;
      int sw = (row & 7) << 4;
      #pragma unroll
      for (int n = 0; n < 8; ++n) {
        float v = fmaxf(acc[m][n][e] + bv[n], 0.f);
        int col = ncg * 128 + n * 16 + cA;
        *(unsigned short*)(cb + ((row * 512 + col * 2) ^ sw)) = f2bf(v);
      }
    }
  __builtin_amdgcn_s_barrier();
  #pragma unroll 4
  for (int r = 0; r < 16; ++r) {
    int row = wid * 32 + r * 2 + (lane >> 5);
    int addr = row * 512 + (((lane & 31) * 16) ^ ((row & 7) << 4));
    bf16x8 v = *(const bf16x8*)(cb + addr);
    *(bf16x8*)(H + (size_t)(row0 + row) * NOUT + col0 + (lane & 31) * 8) = v;
  }
}

// ---------------------------------------------------------------------------
// Grouped GEMM — m201 template port (R11, verbatim). Used for L1 and L3.
// ---------------------------------------------------------------------------
template <int K, int NOUT, bool RELU, bool FINAL>
__launch_bounds__(512, 2)
__global__ void k_gemm(const unsigned short* __restrict__ A,
                       const unsigned short* __restrict__ Wt,
                       const float* __restrict__ bias,
                       unsigned short* __restrict__ H,
                       float* __restrict__ OUT,
                       const int* __restrict__ meta,
                       const int* __restrict__ perm) {
  constexpr int nKT = K / 64;
  __shared__ char lds[131072];

  int NXB = gridDim.x;
  int nwg = NXB * (int)gridDim.y;
  int raw = blockIdx.x + blockIdx.y * NXB;
  int q = nwg >> 3, rr = nwg & 7;
  int xcd = raw & 7, idx = raw >> 3;
  int swz = (xcd < rr ? xcd * (q + 1) : rr * (q + 1) + (xcd - rr) * q) + idx;
  int bx = swz % NXB, by = swz / NXB;

  int row0 = by * 256;
  if (row0 >= meta[26]) return;
  int t = 0;
  while (row0 >= meta[17 + t]) t++;
  int seg = meta[16 + t], cnt = meta[t];
  int tid = threadIdx.x, lane = tid & 63, wid = tid >> 6;
  int wr = (wid >> 2) * 128, wc = (wid & 3) * 64;
  int ah = wid >> 2, bh = (wid & 3) >> 1, clb = (wid & 1) * 64;
  int col0 = bx * 256;
  const char* Ag = (const char*)(A + (size_t)row0 * K);
  const char* Bg = (const char*)(Wt + ((size_t)t * NOUT + col0) * K);

  int gsrc = ((tid & 7) ^ ((tid >> 3) & 7)) * 16;
  const char* aS = Ag + (size_t)(tid >> 3) * (2 * K) + gsrc;
  const char* bS = Bg + (size_t)(tid >> 3) * (2 * K) + gsrc;

  auto stage = [&](int kt, int sub) {
    if (kt >= nKT) return;
    int h = sub & 1, du = kt & 1;
    char* dst = lds + ((sub < 2) ? 0 : 65536) + (du * 2 + h) * 16384 + wid * 1024;
    const char* base = (sub < 2) ? aS : bS;
    const char* src = base + (size_t)(h * 128) * (2 * K) + (size_t)kt * 128;
    async16(dst,        src);
    async16(dst + 8192, src + (size_t)64 * (2 * K));
  };

  f32x4 acc[8][4] = {};
  int rA = lane & 15, qoff = (lane >> 4) * 16, xr = (lane & 7) << 4;

  stage(0, 0); stage(0, 1); stage(0, 2); stage(0, 3); stage(1, 0);
  asm volatile("s_waitcnt vmcnt(2)" ::: "memory");
  __builtin_amdgcn_s_barrier();

  for (int g = 0; g < nKT; ++g) {
    int d = g & 1;
    const char* Au = lds + (d * 2 + ah) * 16384;
    const char* Bu = lds + 65536 + (d * 2 + bh) * 16384;
    bf16x8 a[4], b0[4], b1[4];

    #pragma unroll
    for (int m = 0; m < 4; ++m) {
      int lr = m * 16 + rA;
      a[m] = *(const bf16x8*)(Au + lr * 128 + (qoff ^ xr));
    }
    #pragma unroll
    for (int n = 0; n < 4; ++n) {
      int cl = clb + n * 16 + rA;
      b0[n] = *(const bf16x8*)(Bu + cl * 128 + (qoff ^ xr));
      b1[n] = *(const bf16x8*)(Bu + cl * 128 + ((64 + qoff) ^ xr));
    }
    stage(g + 1, 1);
    asm volatile("s_waitcnt lgkmcnt(8)" ::: "memory");
    __builtin_amdgcn_s_barrier();
    asm volatile("s_waitcnt lgkmcnt(0)" ::: "memory");
    __builtin_amdgcn_s_setprio(1);
    #pragma unroll
    for (int m = 0; m < 4; ++m)
      #pragma unroll
      for (int n = 0; n < 4; ++n)
        acc[m][n] = __builtin_amdgcn_mfma_f32_16x16x32_bf16(a[m], b0[n], acc[m][n], 0, 0, 0);
    __builtin_amdgcn_s_setprio(0);
    __builtin_amdgcn_s_barrier();

    #pragma unroll
    for (int m = 0; m < 4; ++m) {
      int lr = m * 16 + rA;
      a[m] = *(const bf16x8*)(Au + lr * 128 + ((64 + qoff) ^ xr));
    }
    stage(g + 1, 2);
    __builtin_amdgcn_s_barrier();
    asm volatile("s_waitcnt lgkmcnt(0)" ::: "memory");
    __builtin_amdgcn_s_setprio(1);
    #pragma unroll
    for (int m = 0; m < 4; ++m)
      #pragma unroll
      for (int n = 0; n < 4; ++n)
        acc[m][n] = __builtin_amdgcn_mfma_f32_16x16x32_bf16(a[m], b1[n], acc[m][n], 0, 0, 0);
    __builtin_amdgcn_s_setprio(0);
    __builtin_amdgcn_s_barrier();

    #pragma unroll
    for (int m = 0; m < 4; ++m) {
      int lr = 64 + m * 16 + rA;
      a[m] = *(const bf16x8*)(Au + lr * 128 + (qoff ^ xr));
    }
    stage(g + 1, 3);
    __builtin_amdgcn_s_barrier();
    asm volatile("s_waitcnt lgkmcnt(0)" ::: "memory");
    __builtin_amdgcn_s_setprio(1);
    #pragma unroll
    for (int m = 0; m < 4; ++m)
      #pragma unroll
      for (int n = 0; n < 4; ++n)
        acc[4 + m][n] = __builtin_amdgcn_mfma_f32_16x16x32_bf16(a[m], b0[n], acc[4 + m][n], 0, 0, 0);
    __builtin_amdgcn_s_setprio(0);
    __builtin_amdgcn_s_barrier();

    #pragma unroll
    for (int m = 0; m < 4; ++m) {
      int lr = 64 + m * 16 + rA;
      a[m] = *(const bf16x8*)(Au + lr * 128 + ((64 + qoff) ^ xr));
    }
    stage(g + 2, 0);
    __builtin_amdgcn_s_barrier();
    asm volatile("s_waitcnt lgkmcnt(0)" ::: "memory");
    __builtin_amdgcn_s_setprio(1);
    #pragma unroll
    for (int m = 0; m < 4; ++m)
      #pragma unroll
      for (int n = 0; n < 4; ++n)
        acc[4 + m][n] = __builtin_amdgcn_mfma_f32_16x16x32_bf16(a[m], b1[n], acc[4 + m][n], 0, 0, 0);
    __builtin_amdgcn_s_setprio(0);
    if (g + 1 < nKT) {
      if (g + 2 < nKT) asm volatile("s_waitcnt vmcnt(2)" ::: "memory");
      else             asm volatile("s_waitcnt vmcnt(0)" ::: "memory");
    }
    __builtin_amdgcn_s_barrier();
  }

  int cA = lane & 15, rE = (lane >> 4) * 4;
  float bv[4];
  #pragma unroll
  for (int ni = 0; ni < 4; ++ni) bv[ni] = bias[t * NOUT + col0 + wc + ni * 16 + cA];
  char* cb = (char*)lds;

  if (!FINAL) {
    #pragma unroll
    for (int mi = 0; mi < 8; ++mi) {
      int rowoff = (mi >> 2) * 64 + (mi & 3) * 16;
      #pragma unroll
      for (int e = 0; e < 4; ++e) {
        int row = wr + rowoff + rE + e;
        int sw = (row & 7) << 4;
        #pragma unroll
        for (int ni = 0; ni < 4; ++ni) {
          float v = acc[mi][ni][e] + bv[ni];
          if (RELU) v = fmaxf(v, 0.f);
          int col = wc + ni * 16 + cA;
          *(unsigned short*)(cb + ((row * 512 + col * 2) ^ sw)) = f2bf(v);
        }
      }
    }
    __builtin_amdgcn_s_barrier();
    #pragma unroll 4
    for (int r = 0; r < 16; ++r) {
      int row = wid * 32 + r * 2 + (lane >> 5);
      int addr = row * 512 + ((((lane & 31) * 16)) ^ ((row & 7) << 4));
      bf16x8 v = *(const bf16x8*)(cb + addr);
      *(bf16x8*)(H + (size_t)(row0 + row) * NOUT + col0 + (lane & 31) * 8) = v;
    }
  } else {
    int myhalf = (wid & 3) >> 1;
    #pragma unroll
    for (int p = 0; p < 2; ++p) {
      if (myhalf == p) {
        int colh = wc & 127;
        #pragma unroll
        for (int mi = 0; mi < 8; ++mi) {
          int rowoff = (mi >> 2) * 64 + (mi & 3) * 16;
          #pragma unroll
          for (int e = 0; e < 4; ++e) {
            int row = wr + rowoff + rE + e;
            int sw = (row & 7) << 4;
            #pragma unroll
            for (int ni = 0; ni < 4; ++ni) {
              float v = acc[mi][ni][e] + bv[ni];
              if (RELU) v = fmaxf(v, 0.f);
              int col = colh + ni * 16 + cA;
              *(float*)(cb + ((row * 512 + col * 4) ^ sw)) = v;
            }
          }
        }
      }
      __builtin_amdgcn_s_barrier();
      #pragma unroll 4
      for (int r = 0; r < 16; ++r) {
        int row = wid * 32 + r * 2 + (lane >> 5);
        int gr = row0 + row;
        int addr = row * 512 + ((((lane & 31) * 16)) ^ ((row & 7) << 4));
        float4 v = *(const float4*)(cb + addr);
        if (gr - seg < cnt) {
          int pr = perm[gr];
          *(float4*)(OUT + (size_t)pr * NOUT + p * (NOUT / 2) + (lane & 31) * 4) = v;
        }
      }
      if (p == 0) __builtin_amdgcn_s_barrier();
    }
  }
}

extern "C" void kernel_launch(void* const* d_in, const int* in_sizes, int n_in,
                              void* d_out, int out_size, void* d_ws, size_t ws_size,
                              hipStream_t stream) {
  const float* x     = (const float*)d_in[0];
  const int*   types = (const int*)d_in[1];
  const float* W0    = (const float*)d_in[2];
  const float* b0    = (const float*)d_in[3];
  const float* W1    = (const float*)d_in[4];
  const float* b1    = (const float*)d_in[5];
  const float* W2    = (const float*)d_in[6];
  const float* b2    = (const float*)d_in[7];
  float* out = (float*)d_out;
  int n = in_sizes[1];
  int RB = (n + 255) / 256 + TYPES;
  size_t NPAD = (size_t)RB * 256;

  char* ws = (char*)d_ws;
  int* meta = (int*)ws;
  int* perm = (int*)(ws + 1024);
  size_t off = 1024 + NPAD * 4;
  off = (off + 255) & ~(size_t)255;
  unsigned short* wt0 = (unsigned short*)(ws + off); off += (size_t)TYPES * D_H1 * D_IN * 2;
  unsigned short* wt1 = (unsigned short*)(ws + off); off += (size_t)TYPES * D_H2 * D_H1 * 2;
  unsigned short* wt2 = (unsigned short*)(ws + off); off += (size_t)TYPES * D_OUT * D_H2 * 2;
  off = (off + 255) & ~(size_t)255;
  unsigned short* B1 = (unsigned short*)(ws + off); off += NPAD * 512 * 2;  // xs, later h2
  unsigned short* B2 = (unsigned short*)(ws + off); off += NPAD * 512 * 2;  // h1

  int hb = (n + 255) / 256;
  k_init<<<1, 64, 0, stream>>>(meta);
  k_hist<<<hb, 256, 0, stream>>>(types, n, meta);
  k_scan<<<1, 64, 0, stream>>>(meta);
  k_scatter<<<hb, 256, 0, stream>>>(types, n, meta, perm);
  k_gather<<<RB * 32, 256, 0, stream>>>(x, perm, meta, B1);
  k_wtrans_all<<<1120, 256, 0, stream>>>(W0, W1, W2, wt0, wt1, wt2);

  k_gemm<D_IN, D_H1, true,  false><<<dim3(D_H1 / 256, RB), 512, 0, stream>>>(B1, wt0, b0, B2, nullptr, meta, perm);
  k_gemmR<<<dim3(D_H2 / 256, RB), 512, 0, stream>>>(B2, wt1, b1, B1, meta);
  k_gemm<D_H2, D_OUT, false, true ><<<dim3(D_OUT / 256, RB), 512, 0, stream>>>(B1, wt2, b2, nullptr, out, meta, perm);
}

// Round 16
// 424.945 us; speedup vs baseline: 2.0431x; 2.0431x over previous
//
#include <hip/hip_runtime.h>
#include <stdint.h>

typedef float  f32x4  __attribute__((ext_vector_type(4)));
typedef short  bf16x8 __attribute__((ext_vector_type(8)));

#define TYPES 10
#define D_IN  128
#define D_H1  512
#define D_H2  512
#define D_OUT 256

__device__ __forceinline__ unsigned short f2bf(float f) {
  union { float f; unsigned u; } v; v.f = f;
  unsigned u = v.u;
  return (unsigned short)((u + 0x7FFFu + ((u >> 16) & 1u)) >> 16);  // RTNE
}

__device__ __forceinline__ void async16(void* lds, const void* g) {
  __builtin_amdgcn_global_load_lds(
      (const __attribute__((address_space(1))) void*)g,
      (__attribute__((address_space(3))) void*)lds, 16, 0, 0);
}

// meta layout (ints): [0..9] counts, [16..26] padded offsets (offs[10]=total), [32..41] scatter cursors
__global__ void k_init(int* meta) {
  if (threadIdx.x < 48) meta[threadIdx.x] = 0;
}

__global__ void k_hist(const int* __restrict__ types, int n, int* __restrict__ meta) {
  __shared__ int lc[TYPES];
  if (threadIdx.x < TYPES) lc[threadIdx.x] = 0;
  __syncthreads();
  int i = blockIdx.x * 256 + threadIdx.x;
  if (i < n) atomicAdd(&lc[types[i]], 1);
  __syncthreads();
  if (threadIdx.x < TYPES && lc[threadIdx.x]) atomicAdd(&meta[threadIdx.x], lc[threadIdx.x]);
}

__global__ void k_scan(int* meta) {
  if (threadIdx.x == 0) {
    int off = 0;
    for (int t = 0; t < TYPES; ++t) {
      meta[16 + t] = off;
      off += ((meta[t] + 255) >> 8) << 8;   // pad each segment to 256 rows (BM=256)
    }
    meta[26] = off;
  }
}

__global__ void k_scatter(const int* __restrict__ types, int n,
                          int* __restrict__ meta, int* __restrict__ perm) {
  __shared__ int lc[TYPES], lbase[TYPES];
  if (threadIdx.x < TYPES) lc[threadIdx.x] = 0;
  __syncthreads();
  int i = blockIdx.x * 256 + threadIdx.x;
  int t = 0, loc = 0;
  bool ok = i < n;
  if (ok) { t = types[i]; loc = atomicAdd(&lc[t], 1); }
  __syncthreads();
  if (threadIdx.x < TYPES) {
    int c = lc[threadIdx.x];
    lbase[threadIdx.x] = c ? atomicAdd(&meta[32 + threadIdx.x], c) : 0;
  }
  __syncthreads();
  if (ok) perm[meta[16 + t] + lbase[t] + loc] = i;
}

// gather rows into sorted order, fp32 -> bf16; zero the padding rows
__global__ void k_gather(const float* __restrict__ x, const int* __restrict__ perm,
                         const int* __restrict__ meta, unsigned short* __restrict__ xs) {
  int p = blockIdx.x * 8 + (threadIdx.x >> 5);
  if (p >= meta[26]) return;
  int t = 0;
  while (p >= meta[17 + t]) t++;
  int e = (threadIdx.x & 31) * 4;
  unsigned short o0, o1, o2, o3;
  if (p - meta[16 + t] < meta[t]) {
    const float4 v = *(const float4*)(x + (size_t)perm[p] * D_IN + e);
    o0 = f2bf(v.x); o1 = f2bf(v.y); o2 = f2bf(v.z); o3 = f2bf(v.w);
  } else {
    o0 = o1 = o2 = o3 = 0;
  }
  *(ushort4*)(xs + (size_t)p * D_IN + e) = make_ushort4(o0, o1, o2, o3);
}

// All three weight transposes in one launch: W[t] (K x NOUT) fp32 -> Wt[t] (NOUT x K) bf16
__global__ void k_wtrans_all(const float* __restrict__ W0a, const float* __restrict__ W1a,
                             const float* __restrict__ W2a,
                             unsigned short* __restrict__ wt0, unsigned short* __restrict__ wt1,
                             unsigned short* __restrict__ wt2) {
  int b = blockIdx.x;
  const float* W; unsigned short* Wt; int K, NOUT, t, local;
  if (b < 160)      { W = W0a; Wt = wt0; K = 128; NOUT = 512; t = b / 16; local = b % 16; }
  else if (b < 800) { b -= 160; W = W1a; Wt = wt1; K = 512; NOUT = 512; t = b / 64; local = b % 64; }
  else              { b -= 800; W = W2a; Wt = wt2; K = 512; NOUT = 256; t = b / 32; local = b % 32; }
  int ntn = NOUT >> 6;
  int kb = local / ntn, nb = local % ntn;
  __shared__ unsigned short tile[64][65];
  const float* src = W + (size_t)t * K * NOUT + (size_t)(kb * 64) * NOUT + nb * 64;
  int c = threadIdx.x & 63;
  int r0 = threadIdx.x >> 6;
  #pragma unroll
  for (int i = 0; i < 16; ++i) {
    int r = r0 * 16 + i;
    tile[r][c] = f2bf(src[(size_t)r * NOUT + c]);
  }
  __syncthreads();
  unsigned short* dst = Wt + (size_t)t * NOUT * K + (size_t)(nb * 64) * K + kb * 64;
  #pragma unroll
  for (int i = 0; i < 16; ++i) {
    int nn = r0 * 16 + i;
    dst[(size_t)nn * K + c] = tile[c][nn];
  }
}

// ---------------------------------------------------------------------------
// Grouped GEMM — faithful m201 template port (R11; best measured config).
// 256x256 tile, BK=64, 512 thr = 8 waves (2Mx4N), per-wave 128x64 output.
// ---------------------------------------------------------------------------
template <int K, int NOUT, bool RELU, bool FINAL>
__launch_bounds__(512, 2)
__global__ void k_gemm(const unsigned short* __restrict__ A,
                       const unsigned short* __restrict__ Wt,
                       const float* __restrict__ bias,
                       unsigned short* __restrict__ H,
                       float* __restrict__ OUT,
                       const int* __restrict__ meta,
                       const int* __restrict__ perm) {
  constexpr int nKT = K / 64;
  __shared__ char lds[131072];

  // bijective XCD-aware swizzle (m204)
  int NXB = gridDim.x;
  int nwg = NXB * (int)gridDim.y;
  int raw = blockIdx.x + blockIdx.y * NXB;
  int q = nwg >> 3, rr = nwg & 7;
  int xcd = raw & 7, idx = raw >> 3;
  int swz = (xcd < rr ? xcd * (q + 1) : rr * (q + 1) + (xcd - rr) * q) + idx;
  int bx = swz % NXB, by = swz / NXB;

  int row0 = by * 256;
  if (row0 >= meta[26]) return;          // block-uniform early exit
  int t = 0;
  while (row0 >= meta[17 + t]) t++;      // segment offsets are multiples of 256
  int seg = meta[16 + t], cnt = meta[t];
  int tid = threadIdx.x, lane = tid & 63, wid = tid >> 6;
  int wr = (wid >> 2) * 128, wc = (wid & 3) * 64;
  int ah = wid >> 2, bh = (wid & 3) >> 1, clb = (wid & 1) * 64;
  int col0 = bx * 256;
  const char* Ag = (const char*)(A + (size_t)row0 * K);
  const char* Bg = (const char*)(Wt + ((size_t)t * NOUT + col0) * K);

  int gsrc = ((tid & 7) ^ ((tid >> 3) & 7)) * 16;
  const char* aS = Ag + (size_t)(tid >> 3) * (2 * K) + gsrc;
  const char* bS = Bg + (size_t)(tid >> 3) * (2 * K) + gsrc;

  // sub: 0=Ah0, 1=Ah1, 2=Bh0, 3=Bh1 (h = sub&1)
  auto stage = [&](int kt, int sub) {
    if (kt >= nKT) return;
    int h = sub & 1, du = kt & 1;
    char* dst = lds + ((sub < 2) ? 0 : 65536) + (du * 2 + h) * 16384 + wid * 1024;
    const char* base = (sub < 2) ? aS : bS;
    const char* src = base + (size_t)(h * 128) * (2 * K) + (size_t)kt * 128;
    async16(dst,        src);
    async16(dst + 8192, src + (size_t)64 * (2 * K));   // i=1: +64 rows
  };

  f32x4 acc[8][4] = {};
  int rA = lane & 15, qoff = (lane >> 4) * 16, xr = (lane & 7) << 4;

  // prologue: tile 0 complete + Ah0(1); drain tile 0 -> vmcnt(2)
  stage(0, 0); stage(0, 1); stage(0, 2); stage(0, 3); stage(1, 0);
  asm volatile("s_waitcnt vmcnt(2)" ::: "memory");
  __builtin_amdgcn_s_barrier();

  for (int g = 0; g < nKT; ++g) {
    int d = g & 1;
    const char* Au = lds + (d * 2 + ah) * 16384;           // wave's own A-half
    const char* Bu = lds + 65536 + (d * 2 + bh) * 16384;   // wave's own B-half
    bf16x8 a[4], b0[4], b1[4];

    // ---- p0: (mh0, kk0) — 12 reads ----
    #pragma unroll
    for (int m = 0; m < 4; ++m) {
      int lr = m * 16 + rA;
      a[m] = *(const bf16x8*)(Au + lr * 128 + (qoff ^ xr));
    }
    #pragma unroll
    for (int n = 0; n < 4; ++n) {
      int cl = clb + n * 16 + rA;
      b0[n] = *(const bf16x8*)(Bu + cl * 128 + (qoff ^ xr));
      b1[n] = *(const bf16x8*)(Bu + cl * 128 + ((64 + qoff) ^ xr));
    }
    stage(g + 1, 1);                      // Ah1(g+1)
    asm volatile("s_waitcnt lgkmcnt(8)" ::: "memory");   // pace the 12-read burst
    __builtin_amdgcn_s_barrier();
    asm volatile("s_waitcnt lgkmcnt(0)" ::: "memory");
    __builtin_amdgcn_s_setprio(1);
    #pragma unroll
    for (int m = 0; m < 4; ++m)
      #pragma unroll
      for (int n = 0; n < 4; ++n)
        acc[m][n] = __builtin_amdgcn_mfma_f32_16x16x32_bf16(a[m], b0[n], acc[m][n], 0, 0, 0);
    __builtin_amdgcn_s_setprio(0);
    __builtin_amdgcn_s_barrier();

    // ---- p1: (mh0, kk1) — 4 reads ----
    #pragma unroll
    for (int m = 0; m < 4; ++m) {
      int lr = m * 16 + rA;
      a[m] = *(const bf16x8*)(Au + lr * 128 + ((64 + qoff) ^ xr));
    }
    stage(g + 1, 2);                      // Bh0(g+1)
    __builtin_amdgcn_s_barrier();
    asm volatile("s_waitcnt lgkmcnt(0)" ::: "memory");
    __builtin_amdgcn_s_setprio(1);
    #pragma unroll
    for (int m = 0; m < 4; ++m)
      #pragma unroll
      for (int n = 0; n < 4; ++n)
        acc[m][n] = __builtin_amdgcn_mfma_f32_16x16x32_bf16(a[m], b1[n], acc[m][n], 0, 0, 0);
    __builtin_amdgcn_s_setprio(0);
    __builtin_amdgcn_s_barrier();

    // ---- p2: (mh1, kk0) — 4 reads ----
    #pragma unroll
    for (int m = 0; m < 4; ++m) {
      int lr = 64 + m * 16 + rA;
      a[m] = *(const bf16x8*)(Au + lr * 128 + (qoff ^ xr));
    }
    stage(g + 1, 3);                      // Bh1(g+1)
    __builtin_amdgcn_s_barrier();
    asm volatile("s_waitcnt lgkmcnt(0)" ::: "memory");
    __builtin_amdgcn_s_setprio(1);
    #pragma unroll
    for (int m = 0; m < 4; ++m)
      #pragma unroll
      for (int n = 0; n < 4; ++n)
        acc[4 + m][n] = __builtin_amdgcn_mfma_f32_16x16x32_bf16(a[m], b0[n], acc[4 + m][n], 0, 0, 0);
    __builtin_amdgcn_s_setprio(0);
    __builtin_amdgcn_s_barrier();

    // ---- p3: (mh1, kk1) — 4 reads ----
    #pragma unroll
    for (int m = 0; m < 4; ++m) {
      int lr = 64 + m * 16 + rA;
      a[m] = *(const bf16x8*)(Au + lr * 128 + ((64 + qoff) ^ xr));
    }
    stage(g + 2, 0);                      // Ah0(g+2)
    __builtin_amdgcn_s_barrier();
    asm volatile("s_waitcnt lgkmcnt(0)" ::: "memory");
    __builtin_amdgcn_s_setprio(1);
    #pragma unroll
    for (int m = 0; m < 4; ++m)
      #pragma unroll
      for (int n = 0; n < 4; ++n)
        acc[4 + m][n] = __builtin_amdgcn_mfma_f32_16x16x32_bf16(a[m], b1[n], acc[4 + m][n], 0, 0, 0);
    __builtin_amdgcn_s_setprio(0);
    if (g + 1 < nKT) {
      if (g + 2 < nKT) asm volatile("s_waitcnt vmcnt(2)" ::: "memory");
      else             asm volatile("s_waitcnt vmcnt(0)" ::: "memory");
    }
    __builtin_amdgcn_s_barrier();
  }

  // epilogue: acc -> LDS (XOR-swizzled 16B granules) -> coalesced stores.
  // acc row offset: (mi>>2)*64 + (mi&3)*16 (m201 phase order).
  int cA = lane & 15, rE = (lane >> 4) * 4;
  float bv[4];
  #pragma unroll
  for (int ni = 0; ni < 4; ++ni) bv[ni] = bias[t * NOUT + col0 + wc + ni * 16 + cA];
  char* cb = (char*)lds;

  if (!FINAL) {
    #pragma unroll
    for (int mi = 0; mi < 8; ++mi) {
      int rowoff = (mi >> 2) * 64 + (mi & 3) * 16;
      #pragma unroll
      for (int e = 0; e < 4; ++e) {
        int row = wr + rowoff + rE + e;
        int sw = (row & 7) << 4;
        #pragma unroll
        for (int ni = 0; ni < 4; ++ni) {
          float v = acc[mi][ni][e] + bv[ni];
          if (RELU) v = fmaxf(v, 0.f);
          int col = wc + ni * 16 + cA;
          *(unsigned short*)(cb + ((row * 512 + col * 2) ^ sw)) = f2bf(v);
        }
      }
    }
    __builtin_amdgcn_s_barrier();
    #pragma unroll 4
    for (int r = 0; r < 16; ++r) {
      int row = wid * 32 + r * 2 + (lane >> 5);
      int addr = row * 512 + ((((lane & 31) * 16)) ^ ((row & 7) << 4));
      bf16x8 v = *(const bf16x8*)(cb + addr);
      *(bf16x8*)(H + (size_t)(row0 + row) * NOUT + col0 + (lane & 31) * 8) = v;
    }
  } else {
    int myhalf = (wid & 3) >> 1;
    #pragma unroll
    for (int p = 0; p < 2; ++p) {
      if (myhalf == p) {
        int colh = wc & 127;
        #pragma unroll
        for (int mi = 0; mi < 8; ++mi) {
          int rowoff = (mi >> 2) * 64 + (mi & 3) * 16;
          #pragma unroll
          for (int e = 0; e < 4; ++e) {
            int row = wr + rowoff + rE + e;
            int sw = (row & 7) << 4;
            #pragma unroll
            for (int ni = 0; ni < 4; ++ni) {
              float v = acc[mi][ni][e] + bv[ni];
              if (RELU) v = fmaxf(v, 0.f);
              int col = colh + ni * 16 + cA;
              *(float*)(cb + ((row * 512 + col * 4) ^ sw)) = v;
            }
          }
        }
      }
      __builtin_amdgcn_s_barrier();
      #pragma unroll 4
      for (int r = 0; r < 16; ++r) {
        int row = wid * 32 + r * 2 + (lane >> 5);
        int gr = row0 + row;
        int addr = row * 512 + ((((lane & 31) * 16)) ^ ((row & 7) << 4));
        float4 v = *(const float4*)(cb + addr);
        if (gr - seg < cnt) {
          int pr = perm[gr];
          *(float4*)(OUT + (size_t)pr * NOUT + p * (NOUT / 2) + (lane & 31) * 4) = v;
        }
      }
      if (p == 0) __builtin_amdgcn_s_barrier();
    }
  }
}

extern "C" void kernel_launch(void* const* d_in, const int* in_sizes, int n_in,
                              void* d_out, int out_size, void* d_ws, size_t ws_size,
                              hipStream_t stream) {
  const float* x     = (const float*)d_in[0];
  const int*   types = (const int*)d_in[1];
  const float* W0    = (const float*)d_in[2];
  const float* b0    = (const float*)d_in[3];
  const float* W1    = (const float*)d_in[4];
  const float* b1    = (const float*)d_in[5];
  const float* W2    = (const float*)d_in[6];
  const float* b2    = (const float*)d_in[7];
  float* out = (float*)d_out;
  int n = in_sizes[1];
  int RB = (n + 255) / 256 + TYPES;       // worst-case padded 256-row blocks
  size_t NPAD = (size_t)RB * 256;

  char* ws = (char*)d_ws;
  int* meta = (int*)ws;
  int* perm = (int*)(ws + 1024);
  size_t off = 1024 + NPAD * 4;
  off = (off + 255) & ~(size_t)255;
  unsigned short* wt0 = (unsigned short*)(ws + off); off += (size_t)TYPES * D_H1 * D_IN * 2;
  unsigned short* wt1 = (unsigned short*)(ws + off); off += (size_t)TYPES * D_H2 * D_H1 * 2;
  unsigned short* wt2 = (unsigned short*)(ws + off); off += (size_t)TYPES * D_OUT * D_H2 * 2;
  off = (off + 255) & ~(size_t)255;
  unsigned short* B1 = (unsigned short*)(ws + off); off += NPAD * 512 * 2;  // xs, later h2
  unsigned short* B2 = (unsigned short*)(ws + off); off += NPAD * 512 * 2;  // h1

  int hb = (n + 255) / 256;
  k_init<<<1, 64, 0, stream>>>(meta);
  k_hist<<<hb, 256, 0, stream>>>(types, n, meta);
  k_scan<<<1, 64, 0, stream>>>(meta);
  k_scatter<<<hb, 256, 0, stream>>>(types, n, meta, perm);
  k_gather<<<RB * 32, 256, 0, stream>>>(x, perm, meta, B1);
  k_wtrans_all<<<1120, 256, 0, stream>>>(W0, W1, W2, wt0, wt1, wt2);

  k_gemm<D_IN, D_H1, true,  false><<<dim3(D_H1 / 256, RB), 512, 0, stream>>>(B1, wt0, b0, B2, nullptr, meta, perm);
  k_gemm<D_H1, D_H2, true,  false><<<dim3(D_H2 / 256, RB), 512, 0, stream>>>(B2, wt1, b1, B1, nullptr, meta, perm);
  k_gemm<D_H2, D_OUT, false, true ><<<dim3(D_OUT / 256, RB), 512, 0, stream>>>(B1, wt2, b2, nullptr, out, meta, perm);
}